// Round 1
// baseline (579.836 us; speedup 1.0000x reference)
//
#include <hip/hip_runtime.h>

#define NB 8192
#define NF 39
#define ND 16
#define NP 16
#define NH 8
#define NHP 128
#define NTHREADS 256
#define GRID 2048

// LDS layout strides (chosen for bank-conflict freedom / float4 alignment)
#define QV_STRIDE 20   // sQ/sV rows: float4-aligned, gcd(20,32)=4 -> spread
#define KT_STRIDE 44   // sKt rows (transposed k): float4-aligned
#define S_STRIDE  41   // scores/att rows: odd stride -> conflict-free column walks

__global__ __launch_bounds__(NTHREADS, 3)
void autoint_kernel(const int* __restrict__ fidx,
                    const float* __restrict__ emb,
                    const float* __restrict__ Wq,
                    const float* __restrict__ Wk,
                    const float* __restrict__ Wv,
                    const float* __restrict__ Wr,
                    const float* __restrict__ outW,
                    const float* __restrict__ outB,
                    float* __restrict__ out)
{
    __shared__ float sW[4 * 2048];          // Wq,Wk,Wv,Wres: [d][128] each
    __shared__ float sE[NF * 16];           // gathered embeddings [f][d]
    __shared__ float sQ[NF * QV_STRIDE];    // q [f][p]
    __shared__ float sKt[16 * KT_STRIDE];   // k transposed [p][f]
    __shared__ float sV[NF * QV_STRIDE];    // v [f][p]
    __shared__ float sS[NF * S_STRIDE];     // exp(scores) -> att [q][k]
    __shared__ float sRed[4];

    const int t = threadIdx.x;

    // ---- load all 4 weight matrices into LDS once per block ----
    {
        const float4* srcs[4] = {(const float4*)Wq, (const float4*)Wk,
                                 (const float4*)Wv, (const float4*)Wr};
        float4* dst = (float4*)sW;
        #pragma unroll
        for (int m = 0; m < 4; ++m)
            for (int i = t; i < 512; i += NTHREADS)
                dst[m * 512 + i] = srcs[m][i];
    }

    for (int b = blockIdx.x; b < NB; b += gridDim.x) {
        // ---- gather embeddings: 39 rows x 16 floats = 156 float4 ----
        if (t < NF * 4) {
            int f = t >> 2;
            int row = fidx[b * NF + f];
            ((float4*)sE)[t] = ((const float4*)emb)[row * 4 + (t & 3)];
        }
        __syncthreads();   // covers weight load on first sample too

        float zacc = 0.0f;

        for (int h = 0; h < NH; ++h) {
            const int colbase = h * 16;

            // ---- projections q,k,v : tasks (mat,f,p4), 3*39*4 = 468 ----
            for (int o = t; o < 468; o += NTHREADS) {
                int mat = o / 156;
                int rem = o - mat * 156;
                int f  = rem >> 2;
                int p4 = rem & 3;
                int col = colbase + p4 * 4;
                float er[16];
                *(float4*)&er[0]  = *(float4*)&sE[f * 16 + 0];
                *(float4*)&er[4]  = *(float4*)&sE[f * 16 + 4];
                *(float4*)&er[8]  = *(float4*)&sE[f * 16 + 8];
                *(float4*)&er[12] = *(float4*)&sE[f * 16 + 12];
                float4 acc = {0.f, 0.f, 0.f, 0.f};
                const float* wp = sW + mat * 2048 + col;
                #pragma unroll
                for (int d = 0; d < 16; ++d) {
                    float4 wv = *(float4*)&wp[d * 128];
                    acc.x += er[d] * wv.x; acc.y += er[d] * wv.y;
                    acc.z += er[d] * wv.z; acc.w += er[d] * wv.w;
                }
                if (mat == 0) {
                    *(float4*)&sQ[f * QV_STRIDE + p4 * 4] = acc;
                } else if (mat == 1) {
                    int pb = p4 * 4;
                    sKt[(pb + 0) * KT_STRIDE + f] = acc.x;
                    sKt[(pb + 1) * KT_STRIDE + f] = acc.y;
                    sKt[(pb + 2) * KT_STRIDE + f] = acc.z;
                    sKt[(pb + 3) * KT_STRIDE + f] = acc.w;
                } else {
                    *(float4*)&sV[f * QV_STRIDE + p4 * 4] = acc;
                }
            }
            __syncthreads();

            // ---- scores + exp : tasks (i, jq), 39*10 = 390 (j-edge writes pad col 39) ----
            for (int o = t; o < 390; o += NTHREADS) {
                int i  = o / 10;
                int jq = o - i * 10;
                float qr[16];
                *(float4*)&qr[0]  = *(float4*)&sQ[i * QV_STRIDE + 0];
                *(float4*)&qr[4]  = *(float4*)&sQ[i * QV_STRIDE + 4];
                *(float4*)&qr[8]  = *(float4*)&sQ[i * QV_STRIDE + 8];
                *(float4*)&qr[12] = *(float4*)&sQ[i * QV_STRIDE + 12];
                float4 acc = {0.f, 0.f, 0.f, 0.f};
                #pragma unroll
                for (int p = 0; p < 16; ++p) {
                    float4 kv = *(float4*)&sKt[p * KT_STRIDE + jq * 4];
                    acc.x += qr[p] * kv.x; acc.y += qr[p] * kv.y;
                    acc.z += qr[p] * kv.z; acc.w += qr[p] * kv.w;
                }
                float* ss = &sS[i * S_STRIDE + jq * 4];
                // |scores| <= ~1e-3 by Xavier bounds -> exp w/o max-subtract is safe
                ss[0] = __expf(acc.x);
                ss[1] = __expf(acc.y);
                ss[2] = __expf(acc.z);
                ss[3] = __expf(acc.w);
            }
            __syncthreads();

            // ---- softmax over QUERY axis: normalize each column j over rows i ----
            if (t < NF) {
                float s = 0.0f;
                for (int i = 0; i < NF; ++i) s += sS[i * S_STRIDE + t];
                float r = 1.0f / s;
                for (int i = 0; i < NF; ++i) sS[i * S_STRIDE + t] *= r;
            }
            __syncthreads();

            // ---- av + residual + relu + z accumulation : tasks (f,p4) = 156 ----
            if (t < 156) {
                int f  = t >> 2;
                int p4 = t & 3;
                int col = colbase + p4 * 4;
                float4 acc = {0.f, 0.f, 0.f, 0.f};
                for (int j = 0; j < NF; ++j) {
                    float a = sS[f * S_STRIDE + j];
                    float4 vv = *(float4*)&sV[j * QV_STRIDE + p4 * 4];
                    acc.x += a * vv.x; acc.y += a * vv.y;
                    acc.z += a * vv.z; acc.w += a * vv.w;
                }
                float er[16];
                *(float4*)&er[0]  = *(float4*)&sE[f * 16 + 0];
                *(float4*)&er[4]  = *(float4*)&sE[f * 16 + 4];
                *(float4*)&er[8]  = *(float4*)&sE[f * 16 + 8];
                *(float4*)&er[12] = *(float4*)&sE[f * 16 + 12];
                float4 res = {0.f, 0.f, 0.f, 0.f};
                const float* wp = sW + 3 * 2048 + col;
                #pragma unroll
                for (int d = 0; d < 16; ++d) {
                    float4 wv = *(float4*)&wp[d * 128];
                    res.x += er[d] * wv.x; res.y += er[d] * wv.y;
                    res.z += er[d] * wv.z; res.w += er[d] * wv.w;
                }
                float4 mh;
                mh.x = fmaxf(acc.x + res.x, 0.f);
                mh.y = fmaxf(acc.y + res.y, 0.f);
                mh.z = fmaxf(acc.z + res.z, 0.f);
                mh.w = fmaxf(acc.w + res.w, 0.f);
                float4 w4 = *(const float4*)&outW[f * NHP + col];
                zacc += mh.x * w4.x + mh.y * w4.y + mh.z * w4.z + mh.w * w4.w;
            }
            __syncthreads();   // protect sQ/sKt/sV/sS before next head
        }

        // ---- block reduction of zacc, then sigmoid ----
        float z = zacc;
        #pragma unroll
        for (int off = 32; off > 0; off >>= 1)
            z += __shfl_down(z, off);
        if ((t & 63) == 0) sRed[t >> 6] = z;
        __syncthreads();
        if (t == 0) {
            float zz = sRed[0] + sRed[1] + sRed[2] + sRed[3] + outB[0];
            out[b] = 1.0f / (1.0f + __expf(-zz));
        }
        __syncthreads();   // protect sRed/sE before next sample
    }
}

extern "C" void kernel_launch(void* const* d_in, const int* in_sizes, int n_in,
                              void* d_out, int out_size, void* d_ws, size_t ws_size,
                              hipStream_t stream) {
    const int*   fidx = (const int*)d_in[0];
    const float* emb  = (const float*)d_in[1];
    const float* Wq   = (const float*)d_in[2];
    const float* Wk   = (const float*)d_in[3];
    const float* Wv   = (const float*)d_in[4];
    const float* Wr   = (const float*)d_in[5];
    const float* oW   = (const float*)d_in[6];
    const float* oB   = (const float*)d_in[7];
    float* out = (float*)d_out;
    autoint_kernel<<<GRID, NTHREADS, 0, stream>>>(fidx, emb, Wq, Wk, Wv, Wr,
                                                  oW, oB, out);
}

// Round 2
// 457.398 us; speedup vs baseline: 1.2677x; 1.2677x over previous
//
#include <hip/hip_runtime.h>

#define NTHREADS 256
#define GRID 512
#define SPB 16   // samples per block; 512*16 = 8192 = B

// LDS strides (all float4-aligned where b128 is used; <=2-way bank aliasing)
// sE  [40][20]  row pad: f=39 zeroed
// sEt [16][40]  col 39 zeroed
// sTt [4][16][40] per-pass T transposed, col 39 zeroed
// sS  [4][40*44 + 4]  exp(scores); +4 head pad spreads banks for phase D
// sU  [4][40*20 + 4]

__global__ __launch_bounds__(NTHREADS, 2)
void autoint_kernel(const int* __restrict__ fidx,
                    const float* __restrict__ emb,
                    const float* __restrict__ Wq,
                    const float* __restrict__ Wk,
                    const float* __restrict__ Wv,
                    const float* __restrict__ Wr,
                    const float* __restrict__ outW,
                    const float* __restrict__ outB,
                    float* __restrict__ out)
{
    __shared__ float sM[2048];    // M_h = Wq_h Wk_h^T, all 8 heads [h][d][c]
    __shared__ float sWv[2048];
    __shared__ float sWr[2048];
    __shared__ float sE[800];
    __shared__ float sEt[640];
    __shared__ float sTt[2560];
    __shared__ float sS[7056];
    __shared__ float sU[3216];
    __shared__ float sRed[4];

    const int t = threadIdx.x;

    // ---------------- preamble (once per block, amortized over 16 samples) ----
    for (int i = t; i < 512; i += NTHREADS) {
        ((float4*)sWv)[i] = ((const float4*)Wv)[i];
        ((float4*)sWr)[i] = ((const float4*)Wr)[i];
    }
    // M[h][d][c] = sum_p Wq[d][h*16+p] * Wk[c][h*16+p]
    for (int o = t; o < 2048; o += NTHREADS) {
        int h = o >> 8, rem = o & 255, d = rem >> 4, c = rem & 15;
        const float4* wq = (const float4*)(Wq + d * 128 + h * 16);
        const float4* wk = (const float4*)(Wk + c * 128 + h * 16);
        float acc = 0.f;
        #pragma unroll
        for (int k = 0; k < 4; ++k) {
            float4 a = wq[k], bb = wk[k];
            acc += a.x * bb.x + a.y * bb.y + a.z * bb.z + a.w * bb.w;
        }
        sM[h * 256 + d * 16 + c] = acc;
    }
    // zero pads: sE row 39, sEt col 39, sTt col 39 (never overwritten later)
    if (t < 16) { sE[39 * 20 + t] = 0.f; sEt[t * 40 + 39] = 0.f; }
    if (t < 64) { sTt[(t >> 4) * 640 + (t & 15) * 40 + 39] = 0.f; }

    for (int s = 0; s < SPB; ++s) {
        const int b = blockIdx.x * SPB + s;

        // ------------- gather: E and E^T -------------
        if (t < 156) {
            int f = t >> 2, c4 = t & 3;
            int row = fidx[b * 39 + f];
            float4 e4 = ((const float4*)emb)[row * 4 + c4];
            *(float4*)&sE[f * 20 + c4 * 4] = e4;
            int dbase = c4 * 4;
            sEt[(dbase + 0) * 40 + f] = e4.x;
            sEt[(dbase + 1) * 40 + f] = e4.y;
            sEt[(dbase + 2) * 40 + f] = e4.z;
            sEt[(dbase + 3) * 40 + f] = e4.w;
        }
        __syncthreads();

        float zacc = 0.f;

        for (int hp = 0; hp < 2; ++hp) {
            // ---- A: T = E * M_h, stored transposed Tt[c][f] ----
            for (int o = t; o < 624; o += NTHREADS) {
                int h = o / 156, rem = o - h * 156;
                int f = rem >> 2, p4 = rem & 3;
                float er[16];
                *(float4*)&er[0]  = *(float4*)&sE[f * 20 + 0];
                *(float4*)&er[4]  = *(float4*)&sE[f * 20 + 4];
                *(float4*)&er[8]  = *(float4*)&sE[f * 20 + 8];
                *(float4*)&er[12] = *(float4*)&sE[f * 20 + 12];
                const float* mp = &sM[(hp * 4 + h) * 256 + p4 * 4];
                float4 acc = {0.f, 0.f, 0.f, 0.f};
                #pragma unroll
                for (int d = 0; d < 16; ++d) {
                    float4 m4 = *(const float4*)&mp[d * 16];
                    acc.x += er[d] * m4.x; acc.y += er[d] * m4.y;
                    acc.z += er[d] * m4.z; acc.w += er[d] * m4.w;
                }
                float* tp = &sTt[h * 640 + p4 * 160 + f];  // (p4*4+pp)*40 rows
                tp[0]   = acc.x;
                tp[40]  = acc.y;
                tp[80]  = acc.z;
                tp[120] = acc.w;
            }
            __syncthreads();

            // ---- B: S = T * E^T (4x4 outer-product blocks), exp fused ----
            for (int o = t; o < 400; o += NTHREADS) {
                int h = o / 100, rem = o - h * 100;
                int i4 = rem / 10, j4 = rem - i4 * 10;
                const float* tp = &sTt[h * 640 + i4 * 4];
                const float* ep = &sEt[j4 * 4];
                float4 a0 = {0.f,0.f,0.f,0.f}, a1 = a0, a2 = a0, a3 = a0;
                #pragma unroll
                for (int c = 0; c < 16; ++c) {
                    float4 tt = *(const float4*)&tp[c * 40];
                    float4 et = *(const float4*)&ep[c * 40];
                    a0.x += tt.x*et.x; a0.y += tt.x*et.y; a0.z += tt.x*et.z; a0.w += tt.x*et.w;
                    a1.x += tt.y*et.x; a1.y += tt.y*et.y; a1.z += tt.y*et.z; a1.w += tt.y*et.w;
                    a2.x += tt.z*et.x; a2.y += tt.z*et.y; a2.z += tt.z*et.z; a2.w += tt.z*et.w;
                    a3.x += tt.w*et.x; a3.y += tt.w*et.y; a3.z += tt.w*et.z; a3.w += tt.w*et.w;
                }
                // |scores| tiny (Xavier) -> exp without max-subtract is safe
                float* sp = &sS[h * 1764 + i4 * 176 + j4 * 4];
                float4 v;
                v.x=__expf(a0.x); v.y=__expf(a0.y); v.z=__expf(a0.z); v.w=__expf(a0.w);
                *(float4*)&sp[0] = v;
                v.x=__expf(a1.x); v.y=__expf(a1.y); v.z=__expf(a1.z); v.w=__expf(a1.w);
                *(float4*)&sp[44] = v;
                v.x=__expf(a2.x); v.y=__expf(a2.y); v.z=__expf(a2.z); v.w=__expf(a2.w);
                *(float4*)&sp[88] = v;
                v.x=__expf(a3.x); v.y=__expf(a3.y); v.z=__expf(a3.z); v.w=__expf(a3.w);
                *(float4*)&sp[132] = v;
            }
            __syncthreads();

            // ---- C: softmax over QUERY axis -> normalize each column j ----
            if (t < 156) {
                int h = t / 39, j = t - h * 39;
                float* cp = &sS[h * 1764 + j];
                float ssum = 0.f;
                #pragma unroll
                for (int i = 0; i < 39; ++i) ssum += cp[i * 44];
                float r = 1.0f / ssum;
                #pragma unroll
                for (int i = 0; i < 39; ++i) cp[i * 44] *= r;
            }
            __syncthreads();

            // ---- D: U = A * E (4 rows x 4 cols register block) ----
            if (t < 160) {
                int h = t / 40, rem = t - h * 40;
                int fb = rem >> 2, d4 = rem & 3;
                const float* ap = &sS[h * 1764 + fb * 176];
                const float* ep = &sE[d4 * 4];
                float4 u0 = {0.f,0.f,0.f,0.f}, u1 = u0, u2 = u0, u3 = u0;
                #pragma unroll
                for (int j4 = 0; j4 < 10; ++j4) {
                    float4 q0 = *(const float4*)&ap[      j4 * 4];
                    float4 q1 = *(const float4*)&ap[ 44 + j4 * 4];
                    float4 q2 = *(const float4*)&ap[ 88 + j4 * 4];
                    float4 q3 = *(const float4*)&ap[132 + j4 * 4];
                    float4 e0 = *(const float4*)&ep[(j4 * 4 + 0) * 20];
                    float4 e1 = *(const float4*)&ep[(j4 * 4 + 1) * 20];
                    float4 e2 = *(const float4*)&ep[(j4 * 4 + 2) * 20];
                    float4 e3 = *(const float4*)&ep[(j4 * 4 + 3) * 20];
                    u0.x += q0.x*e0.x + q0.y*e1.x + q0.z*e2.x + q0.w*e3.x;
                    u0.y += q0.x*e0.y + q0.y*e1.y + q0.z*e2.y + q0.w*e3.y;
                    u0.z += q0.x*e0.z + q0.y*e1.z + q0.z*e2.z + q0.w*e3.z;
                    u0.w += q0.x*e0.w + q0.y*e1.w + q0.z*e2.w + q0.w*e3.w;
                    u1.x += q1.x*e0.x + q1.y*e1.x + q1.z*e2.x + q1.w*e3.x;
                    u1.y += q1.x*e0.y + q1.y*e1.y + q1.z*e2.y + q1.w*e3.y;
                    u1.z += q1.x*e0.z + q1.y*e1.z + q1.z*e2.z + q1.w*e3.z;
                    u1.w += q1.x*e0.w + q1.y*e1.w + q1.z*e2.w + q1.w*e3.w;
                    u2.x += q2.x*e0.x + q2.y*e1.x + q2.z*e2.x + q2.w*e3.x;
                    u2.y += q2.x*e0.y + q2.y*e1.y + q2.z*e2.y + q2.w*e3.y;
                    u2.z += q2.x*e0.z + q2.y*e1.z + q2.z*e2.z + q2.w*e3.z;
                    u2.w += q2.x*e0.w + q2.y*e1.w + q2.z*e2.w + q2.w*e3.w;
                    u3.x += q3.x*e0.x + q3.y*e1.x + q3.z*e2.x + q3.w*e3.x;
                    u3.y += q3.x*e0.y + q3.y*e1.y + q3.z*e2.y + q3.w*e3.y;
                    u3.z += q3.x*e0.z + q3.y*e1.z + q3.z*e2.z + q3.w*e3.z;
                    u3.w += q3.x*e0.w + q3.y*e1.w + q3.z*e2.w + q3.w*e3.w;
                }
                float* up = &sU[h * 804 + fb * 80 + d4 * 4];
                *(float4*)&up[0]  = u0;
                *(float4*)&up[20] = u1;
                *(float4*)&up[40] = u2;
                *(float4*)&up[60] = u3;
            }
            __syncthreads();

            // ---- E: MH = U*Wv_h + E*Wr_h, relu, dot with outW ----
            for (int o = t; o < 624; o += NTHREADS) {
                int h = o / 156, rem = o - h * 156;
                int f = rem >> 2, p4 = rem & 3;
                int col = (hp * 4 + h) * 16 + p4 * 4;
                float ur[16], er[16];
                *(float4*)&ur[0]  = *(float4*)&sU[h * 804 + f * 20 + 0];
                *(float4*)&ur[4]  = *(float4*)&sU[h * 804 + f * 20 + 4];
                *(float4*)&ur[8]  = *(float4*)&sU[h * 804 + f * 20 + 8];
                *(float4*)&ur[12] = *(float4*)&sU[h * 804 + f * 20 + 12];
                *(float4*)&er[0]  = *(float4*)&sE[f * 20 + 0];
                *(float4*)&er[4]  = *(float4*)&sE[f * 20 + 4];
                *(float4*)&er[8]  = *(float4*)&sE[f * 20 + 8];
                *(float4*)&er[12] = *(float4*)&sE[f * 20 + 12];
                float4 acc = {0.f, 0.f, 0.f, 0.f};
                #pragma unroll
                for (int d = 0; d < 16; ++d) {
                    float4 wv = *(const float4*)&sWv[d * 128 + col];
                    float4 wr = *(const float4*)&sWr[d * 128 + col];
                    acc.x += ur[d] * wv.x + er[d] * wr.x;
                    acc.y += ur[d] * wv.y + er[d] * wr.y;
                    acc.z += ur[d] * wv.z + er[d] * wr.z;
                    acc.w += ur[d] * wv.w + er[d] * wr.w;
                }
                float4 mh;
                mh.x = fmaxf(acc.x, 0.f); mh.y = fmaxf(acc.y, 0.f);
                mh.z = fmaxf(acc.z, 0.f); mh.w = fmaxf(acc.w, 0.f);
                float4 ow = *(const float4*)&outW[f * 128 + col];
                zacc += mh.x*ow.x + mh.y*ow.y + mh.z*ow.z + mh.w*ow.w;
            }
            __syncthreads();
        }

        // ---- block reduction + sigmoid ----
        float z = zacc;
        #pragma unroll
        for (int off = 32; off > 0; off >>= 1)
            z += __shfl_down(z, off);
        if ((t & 63) == 0) sRed[t >> 6] = z;
        __syncthreads();
        if (t == 0) {
            float zz = sRed[0] + sRed[1] + sRed[2] + sRed[3] + outB[0];
            out[b] = 1.0f / (1.0f + __expf(-zz));
        }
        __syncthreads();
    }
}

extern "C" void kernel_launch(void* const* d_in, const int* in_sizes, int n_in,
                              void* d_out, int out_size, void* d_ws, size_t ws_size,
                              hipStream_t stream) {
    const int*   fidx = (const int*)d_in[0];
    const float* emb  = (const float*)d_in[1];
    const float* Wq   = (const float*)d_in[2];
    const float* Wk   = (const float*)d_in[3];
    const float* Wv   = (const float*)d_in[4];
    const float* Wr   = (const float*)d_in[5];
    const float* oW   = (const float*)d_in[6];
    const float* oB   = (const float*)d_in[7];
    float* out = (float*)d_out;
    autoint_kernel<<<GRID, NTHREADS, 0, stream>>>(fidx, emb, Wq, Wk, Wv, Wr,
                                                  oW, oB, out);
}